// Round 2
// baseline (1093.495 us; speedup 1.0000x reference)
//
#include <hip/hip_runtime.h>
#include <math.h>

// ---------------- problem constants ----------------
#define T_TOK 16384   // B*S tokens
#define HDIM  1024
#define IDIM  2048
#define NEXP  8
#define CAP   16384   // per-expert capacity (each token at most once per expert)
#define RT256 (CAP / 256)

typedef __bf16 bf16x8 __attribute__((ext_vector_type(8)));
typedef float  f32x4  __attribute__((ext_vector_type(4)));
typedef unsigned short us8 __attribute__((ext_vector_type(8)));

__device__ __forceinline__ unsigned short f2bf(float f) {
  unsigned int u = __builtin_bit_cast(unsigned int, f);
  u = (u + 0x7FFFu + ((u >> 16) & 1u)) >> 16;   // RNE
  return (unsigned short)u;
}

__device__ __forceinline__ float bf2f(unsigned short u) {
  return __builtin_bit_cast(float, (unsigned int)u << 16);
}

__device__ __forceinline__ void gld16(const void* g, void* l) {
  __builtin_amdgcn_global_load_lds(
      (const __attribute__((address_space(1))) void*)(g),
      (__attribute__((address_space(3))) void*)(l), 16, 0, 0);
}

// read 8 consecutive fp32 from LDS, convert to bf16x8 (RNE)
__device__ __forceinline__ bf16x8 cvt8(const float* p) {
  f32x4 lo = *(const f32x4*)p;
  f32x4 hi = *(const f32x4*)(p + 4);
  us8 t;
  t[0] = f2bf(lo[0]); t[1] = f2bf(lo[1]); t[2] = f2bf(lo[2]); t[3] = f2bf(lo[3]);
  t[4] = f2bf(hi[0]); t[5] = f2bf(hi[1]); t[6] = f2bf(hi[2]); t[7] = f2bf(hi[3]);
  return __builtin_bit_cast(bf16x8, t);
}

// ---------------- tiny utility kernels ----------------
__global__ void zero_out_k(float4* out) {   // one float4 per thread
  out[blockIdx.x * 256 + threadIdx.x] = float4{0.f, 0.f, 0.f, 0.f};
}

__global__ void report_k(float* out, float v, int n) {  // diagnostic: absmax == ws MB
  int idx = blockIdx.x * blockDim.x + threadIdx.x;
  int stride = gridDim.x * blockDim.x;
  for (int i = idx; i < n; i += stride) out[i] = v;
}

// ---------------- fp32 -> bf16 conversion (grid-stride, float4) ----------------
__global__ void cvt_bf16_k(const float* __restrict__ src, unsigned short* __restrict__ dst, int n4) {
  int idx = blockIdx.x * blockDim.x + threadIdx.x;
  int stride = gridDim.x * blockDim.x;
  for (int i = idx; i < n4; i += stride) {
    float4 v = ((const float4*)src)[i];
    ushort4 o;
    o.x = f2bf(v.x); o.y = f2bf(v.y); o.z = f2bf(v.z); o.w = f2bf(v.w);
    ((ushort4*)dst)[i] = o;
  }
}

// ---------------- routing pass 1: fp32 logits, top-2, softmax; also emits xbf ----------------
__global__ void route1_k(const float* __restrict__ x, const float* __restrict__ wg,
                         int* __restrict__ echoice, float* __restrict__ tgate,
                         unsigned short* __restrict__ xbf) {
  __shared__ __align__(16) float wgl[NEXP * HDIM];   // 32 KB
  int tid = threadIdx.x;
  for (int i = tid; i < NEXP * HDIM / 4; i += 256)
    ((float4*)wgl)[i] = ((const float4*)wg)[i];
  __syncthreads();

  int wave = tid >> 6, lane = tid & 63;
  int t = blockIdx.x * 4 + wave;

  float accv[NEXP];
#pragma unroll
  for (int e = 0; e < NEXP; e++) accv[e] = 0.f;
  const float* xr = x + (size_t)t * HDIM;
#pragma unroll 4
  for (int j = 0; j < HDIM / 64; j++) {
    float xv = xr[lane + j * 64];
    if (xbf) xbf[(size_t)t * HDIM + lane + j * 64] = f2bf(xv);
#pragma unroll
    for (int e = 0; e < NEXP; e++) accv[e] += xv * wgl[e * HDIM + lane + j * 64];
  }
#pragma unroll
  for (int off = 1; off < 64; off <<= 1) {
#pragma unroll
    for (int e = 0; e < NEXP; e++) accv[e] += __shfl_xor(accv[e], off, 64);
  }

  if (lane == 0) {
    int e0 = 0; float v0 = accv[0];
#pragma unroll
    for (int e = 1; e < NEXP; e++) if (accv[e] > v0) { v0 = accv[e]; e0 = e; }
    int e1 = -1; float v1 = -3.4e38f;
#pragma unroll
    for (int e = 0; e < NEXP; e++) if (e != e0 && accv[e] > v1) { v1 = accv[e]; e1 = e; }
    float ex = expf(v1 - v0);
    echoice[t] = e0 | (e1 << 8);
    tgate[t * 2]     = 1.f / (1.f + ex);
    tgate[t * 2 + 1] = ex / (1.f + ex);
  }
}

// ---------------- routing pass 2: deterministic per-expert compaction ----------------
__global__ void route2_k(const int* __restrict__ echoice, int* __restrict__ counts,
                         int* __restrict__ etok) {
  int E = blockIdx.x;
  int tid = threadIdx.x, lane = tid & 63, wv = tid >> 6;
  __shared__ int base;
  __shared__ int wsum[4];
  if (tid == 0) base = 0;
  __syncthreads();
  for (int t0 = 0; t0 < T_TOK; t0 += 256) {
    int t = t0 + tid;
    int ec = echoice[t];
    int e0 = ec & 255, e1 = (ec >> 8) & 255;
    bool m = (e0 == E) | (e1 == E);
    int code = t * 2 + (e1 == E ? 1 : 0);
    unsigned long long mask = __ballot(m);
    if (lane == 0) wsum[wv] = __popcll(mask);
    int lpre = __popcll(mask & ((1ull << lane) - 1ull));
    __syncthreads();
    int wbase = 0;
#pragma unroll
    for (int w = 0; w < 4; w++) if (w < wv) wbase += wsum[w];
    int total = wsum[0] + wsum[1] + wsum[2] + wsum[3];
    if (m) etok[E * CAP + base + wbase + lpre] = code;
    __syncthreads();
    if (tid == 0) base += total;
    __syncthreads();
  }
  if (tid == 0) counts[E] = base;
}

// ---------------- grouped GEMM: 256x256 tile, BK=64, minimal 2-phase double-buffer ----------------
// Catalog T3-minimum recipe (m230-V0 / m248v2, 655-682 TF verified on grouped 256^2 K=1024):
//   prologue: STAGE(buf0, t=0); vmcnt(0); barrier;
//   iter t:   STAGE(buf^1, t+1)  -> ds_read cur -> setprio(1) MFMA setprio(0)
//             -> vmcnt(0) -> ONE s_barrier
// Staging latency hides under the 64-MFMA cluster (~620cy/SIMD > HBM ~500cy).
// LDS is fragment-major (proved conflict-free in round 1, BANK_CONFLICT=0):
//   A elem [row][kk*32+q*8+e3] at byte (row>>4)*2048 + kk*1024 + q*256 + (row&15)*16 + e3*2
// so gld_lds staging is linear (tid*16) and every ds_read_b128 is a contiguous
// 1024B wave stream.  8 waves (2Mx4N), per-wave 128x64 output, acc[8][4].
// Fragments read per-kk half to keep live VGPRs ~100 (+128 AGPR acc).
template <int STAGE, int K, int N>
__global__ __launch_bounds__(512)
void gemm2p_k(const unsigned short* __restrict__ A, const unsigned short* __restrict__ W,
              const float* __restrict__ bias, unsigned short* __restrict__ hmid,
              unsigned short* __restrict__ ybf,
              const int* __restrict__ counts, const int* __restrict__ etok) {
  extern __shared__ __align__(16) char smem[];   // 2 x (A 32KB + B 32KB) = 128 KB
  constexpr int NTK = K / 64;
  constexpr int NTC = N / 256;
  int e  = blockIdx.x / (RT256 * NTC);
  int bi = blockIdx.x % (RT256 * NTC);
  int rt = bi / NTC, ct = bi % NTC;
  int cnt = counts[e];
  if (rt * 256 >= cnt) return;

  int tid = threadIdx.x;
  int lane = tid & 63, wv = tid >> 6;
  int wr = wv >> 2, wc = wv & 3;           // 2x4 wave grid, 128x64 per wave
  int quad = lane >> 4, ml = lane & 15;

  // ---- staging pointers: thread covers 4 A-chunks + 4 B-chunks of 16B ----
  // chunk c = tid + 512*j ; ml=c&15, q=(c>>4)&3, gk=c>>6 (g=gk>>1, kk=gk&1)
  // source row = g*16+ml (gathered via etok for A), k-elems kk*32+q*8 .. +8
  int tq = (tid >> 4) & 3, tml = tid & 15, tw = tid >> 6;
  const unsigned short* aA[4];
  const unsigned short* aB[4];
#pragma unroll
  for (int j = 0; j < 4; j++) {
    int gk = tw + 8 * j;                   // 0..31, uniform per wave
    int g = gk >> 1, kk = gk & 1;
    int koff = kk * 32 + tq * 8;
    int r = rt * 256 + g * 16 + tml;
    int code = etok[e * CAP + (r < cnt ? r : cnt - 1)];
    int arow = (STAGE == 1) ? (code >> 1) : code;
    aA[j] = A + (size_t)arow * K + koff;
    int n = ct * 256 + g * 16 + tml;
    aB[j] = W + ((size_t)e * N + n) * K + koff;
  }

  auto stage = [&](int t, int b) {
    char* dst = smem + b * 65536 + tid * 16;
    size_t ko = (size_t)t * 64;
#pragma unroll
    for (int j = 0; j < 4; j++) gld16(aA[j] + ko, dst + j * 8192);
#pragma unroll
    for (int j = 0; j < 4; j++) gld16(aB[j] + ko, dst + 32768 + j * 8192);
  };

  f32x4 acc[8][4] = {};

  // prologue
  stage(0, 0);
  asm volatile("s_waitcnt vmcnt(0)" ::: "memory");
  __builtin_amdgcn_s_barrier();

  int ro = quad * 256 + ml * 16;

#pragma unroll 2
  for (int t = 0; t < NTK; t++) {
    int cur = t & 1;
    if (t + 1 < NTK) stage(t + 1, cur ^ 1);          // issue next-tile loads first
    const char* Abuf = smem + cur * 65536;
    const char* Bbuf = Abuf + 32768;
#pragma unroll
    for (int kk = 0; kk < 2; kk++) {
      bf16x8 av[8], bv[4];
#pragma unroll
      for (int mi = 0; mi < 8; mi++)
        av[mi] = *(const bf16x8*)(Abuf + (wr * 8 + mi) * 2048 + kk * 1024 + ro);
#pragma unroll
      for (int ni = 0; ni < 4; ni++)
        bv[ni] = *(const bf16x8*)(Bbuf + (wc * 4 + ni) * 2048 + kk * 1024 + ro);
      __builtin_amdgcn_s_setprio(1);
#pragma unroll
      for (int mi = 0; mi < 8; mi++)
#pragma unroll
        for (int ni = 0; ni < 4; ni++)
          acc[mi][ni] = __builtin_amdgcn_mfma_f32_16x16x32_bf16(av[mi], bv[ni], acc[mi][ni], 0, 0, 0);
      __builtin_amdgcn_s_setprio(0);
    }
    asm volatile("s_waitcnt vmcnt(0)" ::: "memory");  // next tile landed; reads of cur done
    __builtin_amdgcn_s_barrier();
  }

  // epilogue: C/D layout col = lane&15, row = quad*4 + reg (verified m89)
  int ncol[4]; float bvs[4];
#pragma unroll
  for (int ni = 0; ni < 4; ni++) {
    ncol[ni] = ct * 256 + wc * 64 + ni * 16 + ml;
    bvs[ni] = bias[e * N + ncol[ni]];
  }
#pragma unroll
  for (int mi = 0; mi < 8; mi++) {
    int ms[4], codes[4];
#pragma unroll
    for (int r = 0; r < 4; r++) {
      ms[r] = rt * 256 + wr * 128 + mi * 16 + quad * 4 + r;
      codes[r] = etok[e * CAP + (ms[r] < cnt ? ms[r] : 0)];
    }
#pragma unroll
    for (int ni = 0; ni < 4; ni++) {
#pragma unroll
      for (int r = 0; r < 4; r++) {
        if (ms[r] < cnt) {
          float v = acc[mi][ni][r] + bvs[ni];
          if (STAGE == 1) {
            v = 0.5f * v * (1.0f + erff(v * 0.70710678118654752f));  // exact gelu
            hmid[(size_t)codes[r] * IDIM + ncol[ni]] = f2bf(v);
          } else {
            ybf[(size_t)codes[r] * HDIM + ncol[ni]] = f2bf(v);
          }
        }
      }
    }
  }
}

// ---------------- legacy 128x128x32 grouped GEMM (lean / atomic fallback) ----------------
template <int STAGE, int K, int N, bool A32, bool B32, bool YATOM>
__global__ __launch_bounds__(256)
void gemm_k(const void* __restrict__ Ap_, const void* __restrict__ Wp_,
            const float* __restrict__ bias, unsigned short* __restrict__ hmid,
            unsigned short* __restrict__ ybf, float* __restrict__ out,
            const float* __restrict__ tgate,
            const int* __restrict__ counts, const int* __restrict__ etok) {
  constexpr int NT = N / 128;
  constexpr int ASZ = A32 ? 16384 : 8192;
  constexpr int BSZ = B32 ? 16384 : 8192;
  __shared__ __align__(16) char smem_s[ASZ + BSZ];
  char* As = smem_s;
  char* Bs = smem_s + ASZ;

  int e  = blockIdx.x / (128 * NT);
  int bi = blockIdx.x % (128 * NT);
  int rt = bi / NT, ct = bi % NT;
  int cnt = counts[e];
  if (rt * 128 >= cnt) return;

  int tid = threadIdx.x;
  int lane = tid & 63, wv = tid >> 6;
  int wr = wv >> 1, wc = wv & 1;
  int quad = lane >> 4, ml = lane & 15;

  const char* aptr[4];
  if constexpr (A32) {
    int srow = tid >> 3, seg = tid & 7;
    const float* Af = (const float*)Ap_;
#pragma unroll
    for (int q = 0; q < 4; q++) {
      int r = rt * 128 + q * 32 + srow;
      int code = etok[e * CAP + (r < cnt ? r : cnt - 1)];
      int row = (STAGE == 1) ? (code >> 1) : code;
      aptr[q] = (const char*)(Af + (size_t)row * K + seg * 4);
    }
  } else {
    int srow = tid >> 2, seg = tid & 3;
    const unsigned short* Ab = (const unsigned short*)Ap_;
#pragma unroll
    for (int q = 0; q < 2; q++) {
      int r = rt * 128 + q * 64 + srow;
      int code = etok[e * CAP + (r < cnt ? r : cnt - 1)];
      int row = (STAGE == 1) ? (code >> 1) : code;
      aptr[q] = (const char*)(Ab + (size_t)row * K + seg * 8);
    }
  }
  const char* bptr[4];
  if constexpr (B32) {
    int srow = tid >> 3, seg = tid & 7;
    const float* Wf = (const float*)Wp_;
#pragma unroll
    for (int q = 0; q < 4; q++)
      bptr[q] = (const char*)(Wf + ((size_t)e * N + ct * 128 + q * 32 + srow) * K + seg * 4);
  } else {
    int srow = tid >> 2, seg = tid & 3;
    const unsigned short* Wb = (const unsigned short*)Wp_;
#pragma unroll
    for (int q = 0; q < 2; q++)
      bptr[q] = (const char*)(Wb + ((size_t)e * N + ct * 128 + q * 64 + srow) * K + seg * 8);
  }

  f32x4 acc[4][4] = {};

  for (int k0 = 0; k0 < K; k0 += 32) {
    size_t aoff = (size_t)k0 * (A32 ? 4 : 2);
    size_t boff = (size_t)k0 * (B32 ? 4 : 2);
    if constexpr (A32) {
#pragma unroll
      for (int q = 0; q < 4; q++) gld16(aptr[q] + aoff, As + q * 4096 + tid * 16);
    } else {
#pragma unroll
      for (int q = 0; q < 2; q++) gld16(aptr[q] + aoff, As + q * 4096 + tid * 16);
    }
    if constexpr (B32) {
#pragma unroll
      for (int q = 0; q < 4; q++) gld16(bptr[q] + boff, Bs + q * 4096 + tid * 16);
    } else {
#pragma unroll
      for (int q = 0; q < 2; q++) gld16(bptr[q] + boff, Bs + q * 4096 + tid * 16);
    }
    __syncthreads();

    bf16x8 af[4], bfr[4];
#pragma unroll
    for (int mi = 0; mi < 4; mi++) {
      int row = wr * 64 + mi * 16 + ml;
      if constexpr (A32) af[mi] = cvt8((const float*)As + row * 32 + quad * 8);
      else af[mi] = __builtin_bit_cast(bf16x8, *(const us8*)((const unsigned short*)As + row * 32 + quad * 8));
    }
#pragma unroll
    for (int ni = 0; ni < 4; ni++) {
      int row = wc * 64 + ni * 16 + ml;
      if constexpr (B32) bfr[ni] = cvt8((const float*)Bs + row * 32 + quad * 8);
      else bfr[ni] = __builtin_bit_cast(bf16x8, *(const us8*)((const unsigned short*)Bs + row * 32 + quad * 8));
    }
#pragma unroll
    for (int mi = 0; mi < 4; mi++)
#pragma unroll
      for (int ni = 0; ni < 4; ni++)
        acc[mi][ni] = __builtin_amdgcn_mfma_f32_16x16x32_bf16(af[mi], bfr[ni], acc[mi][ni], 0, 0, 0);
    __syncthreads();
  }

#pragma unroll
  for (int mi = 0; mi < 4; mi++) {
    int ms[4], codes[4];
#pragma unroll
    for (int r = 0; r < 4; r++) {
      ms[r] = rt * 128 + wr * 64 + mi * 16 + quad * 4 + r;
      codes[r] = etok[e * CAP + (ms[r] < cnt ? ms[r] : 0)];
    }
#pragma unroll
    for (int ni = 0; ni < 4; ni++) {
      int n = ct * 128 + wc * 64 + ni * 16 + ml;
      float bvv = bias[e * N + n];
#pragma unroll
      for (int r = 0; r < 4; r++) {
        if (ms[r] < cnt) {
          float v = acc[mi][ni][r] + bvv;
          if (STAGE == 1) {
            v = 0.5f * v * (1.0f + erff(v * 0.70710678118654752f));
            hmid[(size_t)codes[r] * IDIM + n] = f2bf(v);
          } else if (YATOM) {
            atomicAdd(&out[(size_t)(codes[r] >> 1) * HDIM + n], tgate[codes[r]] * v);
          } else {
            ybf[(size_t)codes[r] * HDIM + n] = f2bf(v);
          }
        }
      }
    }
  }
}

// ---------------- combine: out[t] = g0*y[2t] + g1*y[2t+1], y is bf16 ----------------
__global__ void combine_k(const unsigned short* __restrict__ y, const float* __restrict__ tgate,
                          float* __restrict__ out) {
  int idx = blockIdx.x * 256 + threadIdx.x;  // T*H/8 threads
  int t = idx >> 7;
  int c = idx & 127;
  float g0 = tgate[t * 2], g1 = tgate[t * 2 + 1];
  us8 a = *(const us8*)(y + ((size_t)(t * 2) * HDIM) + c * 8);
  us8 b = *(const us8*)(y + ((size_t)(t * 2 + 1) * HDIM) + c * 8);
  float o[8];
#pragma unroll
  for (int i = 0; i < 8; i++) o[i] = g0 * bf2f(a[i]) + g1 * bf2f(b[i]);
  float4* op = (float4*)(out + (size_t)t * HDIM + c * 8);
  op[0] = float4{o[0], o[1], o[2], o[3]};
  op[1] = float4{o[4], o[5], o[6], o[7]};
}

// ---------------- launch ----------------
extern "C" void kernel_launch(void* const* d_in, const int* in_sizes, int n_in,
                              void* d_out, int out_size, void* d_ws, size_t ws_size,
                              hipStream_t stream) {
  const float* x     = (const float*)d_in[0];  // [T, H]
  const float* wg    = (const float*)d_in[1];  // [E, H]
  const float* wfc   = (const float*)d_in[2];  // [E, I, H]
  const float* bfc   = (const float*)d_in[3];  // [E, I]
  const float* wproj = (const float*)d_in[4];  // [E, H, I]
  const float* bproj = (const float*)d_in[5];  // [E, H]
  float* out = (float*)d_out;

  // workspace layout (bytes)
  char* ws = (char*)d_ws;
  size_t off = 0;
  int* counts  = (int*)(ws + off);   off += 4096;
  int* echoice = (int*)(ws + off);   off += (size_t)T_TOK * 4;          // 64 KB
  int* etok    = (int*)(ws + off);   off += (size_t)NEXP * CAP * 4;     // 512 KB
  float* tgate = (float*)(ws + off); off += (size_t)T_TOK * 2 * 4;      // 128 KB
  unsigned short* hmid = (unsigned short*)(ws + off);
  off += (size_t)T_TOK * 2 * IDIM * 2;                                  // 134 MB
  size_t lean_need = off;                                               // ~135 MB
  unsigned short* xbf = (unsigned short*)(ws + off);
  size_t off2 = off + (size_t)T_TOK * HDIM * 2;
  unsigned short* wfcbf = (unsigned short*)(ws + off2);
  off2 += (size_t)NEXP * IDIM * HDIM * 2;
  unsigned short* wprojbf = (unsigned short*)(ws + off2);
  off2 += (size_t)NEXP * HDIM * IDIM * 2;
  size_t full_need = off2;                                              // ~236 MB
  unsigned short* ybf = xbf;   // aliases xbf+wfcbf (dead after GEMM1)

  if (ws_size < lean_need) {
    report_k<<<256, 256, 0, stream>>>(out, (float)(ws_size >> 20), T_TOK * HDIM);
    return;
  }

  bool full = (ws_size >= full_need);

  route1_k<<<T_TOK / 4, 256, 0, stream>>>(x, wg, echoice, tgate, full ? xbf : (unsigned short*)nullptr);
  route2_k<<<NEXP, 256, 0, stream>>>(echoice, counts, etok);

  if (full) {
    // fast path: bf16 operands + minimal-2-phase pipelined 256^2 grouped GEMM
    static bool s_attr = false;
    if (!s_attr) {
      (void)hipFuncSetAttribute((const void*)gemm2p_k<1, HDIM, IDIM>,
                                hipFuncAttributeMaxDynamicSharedMemorySize, 131072);
      (void)hipFuncSetAttribute((const void*)gemm2p_k<2, IDIM, HDIM>,
                                hipFuncAttributeMaxDynamicSharedMemorySize, 131072);
      s_attr = true;
    }
    cvt_bf16_k<<<4096, 256, 0, stream>>>(wfc,   wfcbf,   NEXP * IDIM * HDIM / 4);
    cvt_bf16_k<<<4096, 256, 0, stream>>>(wproj, wprojbf, NEXP * HDIM * IDIM / 4);
    gemm2p_k<1, HDIM, IDIM><<<NEXP * RT256 * (IDIM / 256), 512, 131072, stream>>>(
        xbf, wfcbf, bfc, hmid, ybf, counts, etok);
    gemm2p_k<2, IDIM, HDIM><<<NEXP * RT256 * (HDIM / 256), 512, 131072, stream>>>(
        hmid, wprojbf, bproj, hmid, ybf, counts, etok);
    combine_k<<<T_TOK * HDIM / 8 / 256, 256, 0, stream>>>(ybf, tgate, out);
  } else {
    // lean path: stage fp32 operands, convert at fragment read; atomic epilogue
    zero_out_k<<<T_TOK * HDIM / 1024, 256, 0, stream>>>((float4*)out);
    gemm_k<1, HDIM, IDIM, true, true, true><<<NEXP * 128 * (IDIM / 128), 256, 0, stream>>>(
        x, wfc, bfc, hmid, ybf, out, tgate, counts, etok);
    gemm_k<2, IDIM, HDIM, false, true, true><<<NEXP * 128 * (HDIM / 128), 256, 0, stream>>>(
        hmid, wproj, bproj, hmid, ybf, out, tgate, counts, etok);
  }
}

// Round 3
// 934.503 us; speedup vs baseline: 1.1701x; 1.1701x over previous
//
#include <hip/hip_runtime.h>
#include <math.h>

// ---------------- problem constants ----------------
#define T_TOK 16384   // B*S tokens
#define HDIM  1024
#define IDIM  2048
#define NEXP  8
#define CAP   16384   // per-expert capacity (each token at most once per expert)

typedef __bf16 bf16x8 __attribute__((ext_vector_type(8)));
typedef float  f32x4  __attribute__((ext_vector_type(4)));
typedef unsigned short us8 __attribute__((ext_vector_type(8)));

__device__ __forceinline__ unsigned short f2bf(float f) {
  unsigned int u = __builtin_bit_cast(unsigned int, f);
  u = (u + 0x7FFFu + ((u >> 16) & 1u)) >> 16;   // RNE
  return (unsigned short)u;
}

__device__ __forceinline__ float bf2f(unsigned short u) {
  return __builtin_bit_cast(float, (unsigned int)u << 16);
}

__device__ __forceinline__ void gld16(const void* g, void* l) {
  __builtin_amdgcn_global_load_lds(
      (const __attribute__((address_space(1))) void*)(g),
      (__attribute__((address_space(3))) void*)(l), 16, 0, 0);
}

// read 8 consecutive fp32 from LDS, convert to bf16x8 (RNE)
__device__ __forceinline__ bf16x8 cvt8(const float* p) {
  f32x4 lo = *(const f32x4*)p;
  f32x4 hi = *(const f32x4*)(p + 4);
  us8 t;
  t[0] = f2bf(lo[0]); t[1] = f2bf(lo[1]); t[2] = f2bf(lo[2]); t[3] = f2bf(lo[3]);
  t[4] = f2bf(hi[0]); t[5] = f2bf(hi[1]); t[6] = f2bf(hi[2]); t[7] = f2bf(hi[3]);
  return __builtin_bit_cast(bf16x8, t);
}

// ---------------- tiny utility kernels ----------------
__global__ void zero_out_k(float4* out) {   // one float4 per thread
  out[blockIdx.x * 256 + threadIdx.x] = float4{0.f, 0.f, 0.f, 0.f};
}

__global__ void report_k(float* out, float v, int n) {  // diagnostic: absmax == ws MB
  int idx = blockIdx.x * blockDim.x + threadIdx.x;
  int stride = gridDim.x * blockDim.x;
  for (int i = idx; i < n; i += stride) out[i] = v;
}

// ---------------- fp32 -> bf16 conversion (grid-stride, float4) ----------------
__global__ void cvt_bf16_k(const float* __restrict__ src, unsigned short* __restrict__ dst, int n4) {
  int idx = blockIdx.x * blockDim.x + threadIdx.x;
  int stride = gridDim.x * blockDim.x;
  for (int i = idx; i < n4; i += stride) {
    float4 v = ((const float4*)src)[i];
    ushort4 o;
    o.x = f2bf(v.x); o.y = f2bf(v.y); o.z = f2bf(v.z); o.w = f2bf(v.w);
    ((ushort4*)dst)[i] = o;
  }
}

// ---------------- routing pass 1: fp32 logits, top-2, softmax; also emits xbf ----------------
__global__ void route1_k(const float* __restrict__ x, const float* __restrict__ wg,
                         int* __restrict__ echoice, float* __restrict__ tgate,
                         unsigned short* __restrict__ xbf) {
  __shared__ __align__(16) float wgl[NEXP * HDIM];   // 32 KB
  int tid = threadIdx.x;
  for (int i = tid; i < NEXP * HDIM / 4; i += 256)
    ((float4*)wgl)[i] = ((const float4*)wg)[i];
  __syncthreads();

  int wave = tid >> 6, lane = tid & 63;
  int t = blockIdx.x * 4 + wave;

  float accv[NEXP];
#pragma unroll
  for (int e = 0; e < NEXP; e++) accv[e] = 0.f;
  const float* xr = x + (size_t)t * HDIM;
#pragma unroll 4
  for (int j = 0; j < HDIM / 64; j++) {
    float xv = xr[lane + j * 64];
    if (xbf) xbf[(size_t)t * HDIM + lane + j * 64] = f2bf(xv);
#pragma unroll
    for (int e = 0; e < NEXP; e++) accv[e] += xv * wgl[e * HDIM + lane + j * 64];
  }
#pragma unroll
  for (int off = 1; off < 64; off <<= 1) {
#pragma unroll
    for (int e = 0; e < NEXP; e++) accv[e] += __shfl_xor(accv[e], off, 64);
  }

  if (lane == 0) {
    int e0 = 0; float v0 = accv[0];
#pragma unroll
    for (int e = 1; e < NEXP; e++) if (accv[e] > v0) { v0 = accv[e]; e0 = e; }
    int e1 = -1; float v1 = -3.4e38f;
#pragma unroll
    for (int e = 0; e < NEXP; e++) if (e != e0 && accv[e] > v1) { v1 = accv[e]; e1 = e; }
    float ex = expf(v1 - v0);
    echoice[t] = e0 | (e1 << 8);
    tgate[t * 2]     = 1.f / (1.f + ex);
    tgate[t * 2 + 1] = ex / (1.f + ex);
  }
}

// ---------------- routing pass 2: deterministic per-expert compaction ----------------
__global__ void route2_k(const int* __restrict__ echoice, int* __restrict__ counts,
                         int* __restrict__ etok) {
  int E = blockIdx.x;
  int tid = threadIdx.x, lane = tid & 63, wv = tid >> 6;
  __shared__ int base;
  __shared__ int wsum[4];
  if (tid == 0) base = 0;
  __syncthreads();
  for (int t0 = 0; t0 < T_TOK; t0 += 256) {
    int t = t0 + tid;
    int ec = echoice[t];
    int e0 = ec & 255, e1 = (ec >> 8) & 255;
    bool m = (e0 == E) | (e1 == E);
    int code = t * 2 + (e1 == E ? 1 : 0);
    unsigned long long mask = __ballot(m);
    if (lane == 0) wsum[wv] = __popcll(mask);
    int lpre = __popcll(mask & ((1ull << lane) - 1ull));
    __syncthreads();
    int wbase = 0;
#pragma unroll
    for (int w = 0; w < 4; w++) if (w < wv) wbase += wsum[w];
    int total = wsum[0] + wsum[1] + wsum[2] + wsum[3];
    if (m) etok[E * CAP + base + wbase + lpre] = code;
    __syncthreads();
    if (tid == 0) base += total;
    __syncthreads();
  }
  if (tid == 0) counts[E] = base;
}

// ---------------- grouped GEMM (128x128x32 tile, m97 schedule, conflict-free LDS) ----------------
// ROUND-3 CHANGE vs the 276us round-0 kernel: ONLY the bf16 LDS layout.
//   Old: row-major [128][32] bf16 -> fragment ds_read_b128 was an 8-way bank
//        conflict (16 lanes at stride 64B), SQ_LDS_BANK_CONFLICT = 1.7e7.
//   New: fragment-major [g:8][quad:4][ml:16] x 16B (row = g*16+ml, k-seg = quad).
//        gld_lds staging stays LINEAR (tid*16, rule #21) -- the *global source*
//        address is permuted instead (m173 pre-swizzled-source pattern); every
//        fragment read is a contiguous 1024B wave stream at base + lane*16.
//        Proven conflict-free in r1/r2 (BANK_CONFLICT = 0).
// Schedule / occupancy / grid identical to round 0 (2 barriers per K-step,
// 256 thr, 16 KB LDS, ~2.5 blocks/CU giving cross-block TLP per m114).
template <int STAGE, int K, int N, bool A32, bool B32, bool YATOM>
__global__ __launch_bounds__(256)
void gemm_k(const void* __restrict__ Ap_, const void* __restrict__ Wp_,
            const float* __restrict__ bias, unsigned short* __restrict__ hmid,
            unsigned short* __restrict__ ybf, float* __restrict__ out,
            const float* __restrict__ tgate,
            const int* __restrict__ counts, const int* __restrict__ etok) {
  constexpr int NT = N / 128;
  constexpr int ASZ = A32 ? 16384 : 8192;
  constexpr int BSZ = B32 ? 16384 : 8192;
  __shared__ __align__(16) char smem[ASZ + BSZ];
  char* As = smem;
  char* Bs = smem + ASZ;

  int e  = blockIdx.x / (128 * NT);
  int bi = blockIdx.x % (128 * NT);
  int rt = bi / NT, ct = bi % NT;
  int cnt = counts[e];
  if (rt * 128 >= cnt) return;

  int tid = threadIdx.x;
  int lane = tid & 63, wv = tid >> 6;
  int wr = wv >> 1, wc = wv & 1;          // 2x2 wave grid, 64x64 per wave
  int quad = lane >> 4, ml = lane & 15;

  // fragment-major staging decomposition: thread tid covers LDS bytes tid*16
  // (+q*4096): g_local = tid>>6, k-seg fq = (tid>>4)&3, row-in-group fml = tid&15
  int fml = tid & 15, fq = (tid >> 4) & 3, fg = tid >> 6;

  // ---- staging pointers ----
  const char* aptr[4];
  if constexpr (A32) {
    int srow = tid >> 3, seg = tid & 7;   // 32 rows per quarter, 8x16B per row
    const float* Af = (const float*)Ap_;
#pragma unroll
    for (int q = 0; q < 4; q++) {
      int r = rt * 128 + q * 32 + srow;
      int code = etok[e * CAP + (r < cnt ? r : cnt - 1)];
      int row = (STAGE == 1) ? (code >> 1) : code;
      aptr[q] = (const char*)(Af + (size_t)row * K + seg * 4);
    }
  } else {
    const unsigned short* Ab = (const unsigned short*)Ap_;
#pragma unroll
    for (int q = 0; q < 2; q++) {
      int r = rt * 128 + (q * 4 + fg) * 16 + fml;    // fragment-major source row
      int code = etok[e * CAP + (r < cnt ? r : cnt - 1)];
      int row = (STAGE == 1) ? (code >> 1) : code;
      aptr[q] = (const char*)(Ab + (size_t)row * K + fq * 8);
    }
  }
  const char* bptr[4];
  if constexpr (B32) {
    int srow = tid >> 3, seg = tid & 7;
    const float* Wf = (const float*)Wp_;
#pragma unroll
    for (int q = 0; q < 4; q++)
      bptr[q] = (const char*)(Wf + ((size_t)e * N + ct * 128 + q * 32 + srow) * K + seg * 4);
  } else {
    const unsigned short* Wb = (const unsigned short*)Wp_;
#pragma unroll
    for (int q = 0; q < 2; q++)
      bptr[q] = (const char*)(Wb + ((size_t)e * N + ct * 128 + (q * 4 + fg) * 16 + fml) * K + fq * 8);
  }

  f32x4 acc[4][4] = {};

  for (int k0 = 0; k0 < K; k0 += 32) {
    size_t aoff = (size_t)k0 * (A32 ? 4 : 2);
    size_t boff = (size_t)k0 * (B32 ? 4 : 2);
    if constexpr (A32) {
#pragma unroll
      for (int q = 0; q < 4; q++) gld16(aptr[q] + aoff, As + q * 4096 + tid * 16);
    } else {
#pragma unroll
      for (int q = 0; q < 2; q++) gld16(aptr[q] + aoff, As + q * 4096 + tid * 16);
    }
    if constexpr (B32) {
#pragma unroll
      for (int q = 0; q < 4; q++) gld16(bptr[q] + boff, Bs + q * 4096 + tid * 16);
    } else {
#pragma unroll
      for (int q = 0; q < 2; q++) gld16(bptr[q] + boff, Bs + q * 4096 + tid * 16);
    }
    __syncthreads();

    bf16x8 af[4], bfr[4];
#pragma unroll
    for (int mi = 0; mi < 4; mi++) {
      if constexpr (A32) {
        int row = wr * 64 + mi * 16 + ml;
        af[mi] = cvt8((const float*)As + row * 32 + quad * 8);
      } else {
        // fragment-major: g = wr*4+mi, contiguous 1024B wave stream (0 conflicts)
        af[mi] = __builtin_bit_cast(bf16x8, *(const us8*)(As + (wr * 4 + mi) * 1024 + lane * 16));
      }
    }
#pragma unroll
    for (int ni = 0; ni < 4; ni++) {
      if constexpr (B32) {
        int row = wc * 64 + ni * 16 + ml;
        bfr[ni] = cvt8((const float*)Bs + row * 32 + quad * 8);
      } else {
        bfr[ni] = __builtin_bit_cast(bf16x8, *(const us8*)(Bs + (wc * 4 + ni) * 1024 + lane * 16));
      }
    }
#pragma unroll
    for (int mi = 0; mi < 4; mi++)
#pragma unroll
      for (int ni = 0; ni < 4; ni++)
        acc[mi][ni] = __builtin_amdgcn_mfma_f32_16x16x32_bf16(af[mi], bfr[ni], acc[mi][ni], 0, 0, 0);
    __syncthreads();
  }

  // epilogue: C/D layout (verified m89): col = lane&15, row = quad*4 + reg
#pragma unroll
  for (int mi = 0; mi < 4; mi++) {
    int ms[4], codes[4];
#pragma unroll
    for (int r = 0; r < 4; r++) {
      ms[r] = rt * 128 + wr * 64 + mi * 16 + quad * 4 + r;
      codes[r] = etok[e * CAP + (ms[r] < cnt ? ms[r] : 0)];
    }
#pragma unroll
    for (int ni = 0; ni < 4; ni++) {
      int n = ct * 128 + wc * 64 + ni * 16 + ml;
      float bv = bias[e * N + n];
#pragma unroll
      for (int r = 0; r < 4; r++) {
        if (ms[r] < cnt) {
          float v = acc[mi][ni][r] + bv;
          if (STAGE == 1) {
            v = 0.5f * v * (1.0f + erff(v * 0.70710678118654752f));  // exact gelu
            hmid[(size_t)codes[r] * IDIM + n] = f2bf(v);
          } else if (YATOM) {
            atomicAdd(&out[(size_t)(codes[r] >> 1) * HDIM + n], tgate[codes[r]] * v);
          } else {
            ybf[(size_t)codes[r] * HDIM + n] = f2bf(v);
          }
        }
      }
    }
  }
}

// ---------------- combine: out[t] = g0*y[2t] + g1*y[2t+1], y is bf16 ----------------
__global__ void combine_k(const unsigned short* __restrict__ y, const float* __restrict__ tgate,
                          float* __restrict__ out) {
  int idx = blockIdx.x * 256 + threadIdx.x;  // T*H/8 threads
  int t = idx >> 7;                          // H/8 = 128 chunks per token
  int c = idx & 127;
  float g0 = tgate[t * 2], g1 = tgate[t * 2 + 1];
  us8 a = *(const us8*)(y + ((size_t)(t * 2) * HDIM) + c * 8);
  us8 b = *(const us8*)(y + ((size_t)(t * 2 + 1) * HDIM) + c * 8);
  float o[8];
#pragma unroll
  for (int i = 0; i < 8; i++) o[i] = g0 * bf2f(a[i]) + g1 * bf2f(b[i]);
  float4* op = (float4*)(out + (size_t)t * HDIM + c * 8);
  op[0] = float4{o[0], o[1], o[2], o[3]};
  op[1] = float4{o[4], o[5], o[6], o[7]};
}

// ---------------- launch ----------------
extern "C" void kernel_launch(void* const* d_in, const int* in_sizes, int n_in,
                              void* d_out, int out_size, void* d_ws, size_t ws_size,
                              hipStream_t stream) {
  const float* x     = (const float*)d_in[0];  // [T, H]
  const float* wg    = (const float*)d_in[1];  // [E, H]
  const float* wfc   = (const float*)d_in[2];  // [E, I, H]
  const float* bfc   = (const float*)d_in[3];  // [E, I]
  const float* wproj = (const float*)d_in[4];  // [E, H, I]
  const float* bproj = (const float*)d_in[5];  // [E, H]
  float* out = (float*)d_out;

  // workspace layout (bytes)
  char* ws = (char*)d_ws;
  size_t off = 0;
  int* counts  = (int*)(ws + off);   off += 4096;
  int* echoice = (int*)(ws + off);   off += (size_t)T_TOK * 4;          // 64 KB
  int* etok    = (int*)(ws + off);   off += (size_t)NEXP * CAP * 4;     // 512 KB
  float* tgate = (float*)(ws + off); off += (size_t)T_TOK * 2 * 4;      // 128 KB
  unsigned short* hmid = (unsigned short*)(ws + off);
  off += (size_t)T_TOK * 2 * IDIM * 2;                                  // 134 MB
  size_t lean_need = off;                                               // ~135 MB
  unsigned short* xbf = (unsigned short*)(ws + off);
  size_t off2 = off + (size_t)T_TOK * HDIM * 2;
  unsigned short* wfcbf = (unsigned short*)(ws + off2);
  off2 += (size_t)NEXP * IDIM * HDIM * 2;
  unsigned short* wprojbf = (unsigned short*)(ws + off2);
  off2 += (size_t)NEXP * HDIM * IDIM * 2;
  size_t full_need = off2;                                              // ~236 MB
  unsigned short* ybf = xbf;   // aliases xbf+wfcbf (dead after GEMM1)

  if (ws_size < lean_need) {
    report_k<<<256, 256, 0, stream>>>(out, (float)(ws_size >> 20), T_TOK * HDIM);
    return;
  }

  bool full = (ws_size >= full_need);

  route1_k<<<T_TOK / 4, 256, 0, stream>>>(x, wg, echoice, tgate, full ? xbf : (unsigned short*)nullptr);
  route2_k<<<NEXP, 256, 0, stream>>>(echoice, counts, etok);

  if (full) {
    // fast path: bf16 operands; non-atomic epilogue via ybf + combine
    cvt_bf16_k<<<4096, 256, 0, stream>>>(wfc,   wfcbf,   NEXP * IDIM * HDIM / 4);
    cvt_bf16_k<<<4096, 256, 0, stream>>>(wproj, wprojbf, NEXP * HDIM * IDIM / 4);
    gemm_k<1, HDIM, IDIM, false, false, false><<<NEXP * 128 * (IDIM / 128), 256, 0, stream>>>(
        xbf, wfcbf, bfc, hmid, ybf, out, tgate, counts, etok);
    gemm_k<2, IDIM, HDIM, false, false, false><<<NEXP * 128 * (HDIM / 128), 256, 0, stream>>>(
        hmid, wprojbf, bproj, hmid, ybf, out, tgate, counts, etok);
    combine_k<<<T_TOK * HDIM / 8 / 256, 256, 0, stream>>>(ybf, tgate, out);
  } else {
    // lean path: stage fp32 operands, convert at fragment read; atomic epilogue
    zero_out_k<<<T_TOK * HDIM / 1024, 256, 0, stream>>>((float4*)out);
    gemm_k<1, HDIM, IDIM, true, true, true><<<NEXP * 128 * (IDIM / 128), 256, 0, stream>>>(
        x, wfc, bfc, hmid, ybf, out, tgate, counts, etok);
    gemm_k<2, IDIM, HDIM, false, true, true><<<NEXP * 128 * (HDIM / 128), 256, 0, stream>>>(
        hmid, wproj, bproj, hmid, ybf, out, tgate, counts, etok);
  }
}

// Round 4
// 719.807 us; speedup vs baseline: 1.5191x; 1.2983x over previous
//
#include <hip/hip_runtime.h>
#include <math.h>

// ---------------- problem constants ----------------
#define T_TOK 16384   // B*S tokens
#define HDIM  1024
#define IDIM  2048
#define NEXP  8
#define CAP   16384   // per-expert capacity (each token at most once per expert)

typedef __bf16 bf16x8 __attribute__((ext_vector_type(8)));
typedef float  f32x4  __attribute__((ext_vector_type(4)));
typedef unsigned short us8 __attribute__((ext_vector_type(8)));

__device__ __forceinline__ unsigned short f2bf(float f) {
  unsigned int u = __builtin_bit_cast(unsigned int, f);
  u = (u + 0x7FFFu + ((u >> 16) & 1u)) >> 16;   // RNE
  return (unsigned short)u;
}

__device__ __forceinline__ float bf2f(unsigned short u) {
  return __builtin_bit_cast(float, (unsigned int)u << 16);
}

__device__ __forceinline__ void gld16(const void* g, void* l) {
  __builtin_amdgcn_global_load_lds(
      (const __attribute__((address_space(1))) void*)(g),
      (__attribute__((address_space(3))) void*)(l), 16, 0, 0);
}

// read 8 consecutive fp32 from LDS, convert to bf16x8 (RNE)
__device__ __forceinline__ bf16x8 cvt8(const float* p) {
  f32x4 lo = *(const f32x4*)p;
  f32x4 hi = *(const f32x4*)(p + 4);
  us8 t;
  t[0] = f2bf(lo[0]); t[1] = f2bf(lo[1]); t[2] = f2bf(lo[2]); t[3] = f2bf(lo[3]);
  t[4] = f2bf(hi[0]); t[5] = f2bf(hi[1]); t[6] = f2bf(hi[2]); t[7] = f2bf(hi[3]);
  return __builtin_bit_cast(bf16x8, t);
}

// ---------------- tiny utility kernels ----------------
__global__ void zero_out_k(float4* out) {   // one float4 per thread
  out[blockIdx.x * 256 + threadIdx.x] = float4{0.f, 0.f, 0.f, 0.f};
}

__global__ void report_k(float* out, float v, int n) {  // diagnostic: absmax == ws MB
  int idx = blockIdx.x * blockDim.x + threadIdx.x;
  int stride = gridDim.x * blockDim.x;
  for (int i = idx; i < n; i += stride) out[i] = v;
}

// ---------------- fp32 -> bf16 conversion (grid-stride, float4) ----------------
__global__ void cvt_bf16_k(const float* __restrict__ src, unsigned short* __restrict__ dst, int n4) {
  int idx = blockIdx.x * blockDim.x + threadIdx.x;
  int stride = gridDim.x * blockDim.x;
  for (int i = idx; i < n4; i += stride) {
    float4 v = ((const float4*)src)[i];
    ushort4 o;
    o.x = f2bf(v.x); o.y = f2bf(v.y); o.z = f2bf(v.z); o.w = f2bf(v.w);
    ((ushort4*)dst)[i] = o;
  }
}

// ---------------- routing pass 1: fp32 logits, top-2, softmax; also emits xbf ----------------
__global__ void route1_k(const float* __restrict__ x, const float* __restrict__ wg,
                         int* __restrict__ echoice, float* __restrict__ tgate,
                         unsigned short* __restrict__ xbf) {
  __shared__ __align__(16) float wgl[NEXP * HDIM];   // 32 KB
  int tid = threadIdx.x;
  for (int i = tid; i < NEXP * HDIM / 4; i += 256)
    ((float4*)wgl)[i] = ((const float4*)wg)[i];
  __syncthreads();

  int wave = tid >> 6, lane = tid & 63;
  int t = blockIdx.x * 4 + wave;

  float accv[NEXP];
#pragma unroll
  for (int e = 0; e < NEXP; e++) accv[e] = 0.f;
  const float* xr = x + (size_t)t * HDIM;
#pragma unroll 4
  for (int j = 0; j < HDIM / 64; j++) {
    float xv = xr[lane + j * 64];
    if (xbf) xbf[(size_t)t * HDIM + lane + j * 64] = f2bf(xv);
#pragma unroll
    for (int e = 0; e < NEXP; e++) accv[e] += xv * wgl[e * HDIM + lane + j * 64];
  }
#pragma unroll
  for (int off = 1; off < 64; off <<= 1) {
#pragma unroll
    for (int e = 0; e < NEXP; e++) accv[e] += __shfl_xor(accv[e], off, 64);
  }

  if (lane == 0) {
    int e0 = 0; float v0 = accv[0];
#pragma unroll
    for (int e = 1; e < NEXP; e++) if (accv[e] > v0) { v0 = accv[e]; e0 = e; }
    int e1 = -1; float v1 = -3.4e38f;
#pragma unroll
    for (int e = 0; e < NEXP; e++) if (e != e0 && accv[e] > v1) { v1 = accv[e]; e1 = e; }
    float ex = expf(v1 - v0);
    echoice[t] = e0 | (e1 << 8);
    tgate[t * 2]     = 1.f / (1.f + ex);
    tgate[t * 2 + 1] = ex / (1.f + ex);
  }
}

// ---------------- routing pass 2: deterministic per-expert compaction ----------------
__global__ void route2_k(const int* __restrict__ echoice, int* __restrict__ counts,
                         int* __restrict__ etok) {
  int E = blockIdx.x;
  int tid = threadIdx.x, lane = tid & 63, wv = tid >> 6;
  __shared__ int base;
  __shared__ int wsum[4];
  if (tid == 0) base = 0;
  __syncthreads();
  for (int t0 = 0; t0 < T_TOK; t0 += 256) {
    int t = t0 + tid;
    int ec = echoice[t];
    int e0 = ec & 255, e1 = (ec >> 8) & 255;
    bool m = (e0 == E) | (e1 == E);
    int code = t * 2 + (e1 == E ? 1 : 0);
    unsigned long long mask = __ballot(m);
    if (lane == 0) wsum[wv] = __popcll(mask);
    int lpre = __popcll(mask & ((1ull << lane) - 1ull));
    __syncthreads();
    int wbase = 0;
#pragma unroll
    for (int w = 0; w < 4; w++) if (w < wv) wbase += wsum[w];
    int total = wsum[0] + wsum[1] + wsum[2] + wsum[3];
    if (m) etok[E * CAP + base + wbase + lpre] = code;
    __syncthreads();
    if (tid == 0) base += total;
    __syncthreads();
  }
  if (tid == 0) counts[E] = base;
}

// ---------------- grouped GEMM (128x128x32 tile, m97 recipe) ----------------
// ROUND-4: exact round-0 kernel (row-major LDS, BK=32 -- empirically the best
// config for this 2-barrier structure; r1/r2/r3 pipeline & layout experiments
// all regressed) + ONE graft: T1 XCD-aware bijective block swizzle
// (swz = (bid&7)*(nwg/8) + bid>>3, nwg%8==0 on both grids).  Each XCD then
// owns a contiguous run of tiles (same expert/rt), keeping the gathered
// A-panel (256 KB) hot in that XCD's private L2 across its ct-tiles.
template <int STAGE, int K, int N, bool A32, bool B32, bool YATOM>
__global__ __launch_bounds__(256)
void gemm_k(const void* __restrict__ Ap_, const void* __restrict__ Wp_,
            const float* __restrict__ bias, unsigned short* __restrict__ hmid,
            unsigned short* __restrict__ ybf, float* __restrict__ out,
            const float* __restrict__ tgate,
            const int* __restrict__ counts, const int* __restrict__ etok) {
  constexpr int NT = N / 128;
  constexpr int ASZ = A32 ? 16384 : 8192;   // bytes: 128 rows x 32 elems
  constexpr int BSZ = B32 ? 16384 : 8192;
  __shared__ __align__(16) char smem[ASZ + BSZ];
  char* As = smem;
  char* Bs = smem + ASZ;

  // T1: XCD-aware bijective swizzle (8 XCDs, grid % 8 == 0 by construction)
  int nwg = gridDim.x;
  int bid = blockIdx.x;
  int swz = (bid & 7) * (nwg >> 3) + (bid >> 3);

  int e  = swz / (128 * NT);
  int bi = swz % (128 * NT);
  int rt = bi / NT, ct = bi % NT;
  int cnt = counts[e];
  if (rt * 128 >= cnt) return;

  int tid = threadIdx.x;
  int lane = tid & 63, wv = tid >> 6;
  int wr = wv >> 1, wc = wv & 1;          // 2x2 wave grid, 64x64 per wave
  int quad = lane >> 4, ml = lane & 15;

  // ---- staging pointers (LDS byte offset is q*4096 + tid*16 for both widths) ----
  const char* aptr[4];
  if constexpr (A32) {
    int srow = tid >> 3, seg = tid & 7;   // 32 rows per quarter, 8x16B per row
    const float* Af = (const float*)Ap_;
#pragma unroll
    for (int q = 0; q < 4; q++) {
      int r = rt * 128 + q * 32 + srow;
      int code = etok[e * CAP + (r < cnt ? r : cnt - 1)];
      int row = (STAGE == 1) ? (code >> 1) : code;
      aptr[q] = (const char*)(Af + (size_t)row * K + seg * 4);
    }
  } else {
    int srow = tid >> 2, seg = tid & 3;   // 64 rows per half, 4x16B per row
    const unsigned short* Ab = (const unsigned short*)Ap_;
#pragma unroll
    for (int q = 0; q < 2; q++) {
      int r = rt * 128 + q * 64 + srow;
      int code = etok[e * CAP + (r < cnt ? r : cnt - 1)];
      int row = (STAGE == 1) ? (code >> 1) : code;
      aptr[q] = (const char*)(Ab + (size_t)row * K + seg * 8);
    }
  }
  const char* bptr[4];
  if constexpr (B32) {
    int srow = tid >> 3, seg = tid & 7;
    const float* Wf = (const float*)Wp_;
#pragma unroll
    for (int q = 0; q < 4; q++)
      bptr[q] = (const char*)(Wf + ((size_t)e * N + ct * 128 + q * 32 + srow) * K + seg * 4);
  } else {
    int srow = tid >> 2, seg = tid & 3;
    const unsigned short* Wb = (const unsigned short*)Wp_;
#pragma unroll
    for (int q = 0; q < 2; q++)
      bptr[q] = (const char*)(Wb + ((size_t)e * N + ct * 128 + q * 64 + srow) * K + seg * 8);
  }

  f32x4 acc[4][4] = {};

  for (int k0 = 0; k0 < K; k0 += 32) {
    size_t aoff = (size_t)k0 * (A32 ? 4 : 2);
    size_t boff = (size_t)k0 * (B32 ? 4 : 2);
    if constexpr (A32) {
#pragma unroll
      for (int q = 0; q < 4; q++) gld16(aptr[q] + aoff, As + q * 4096 + tid * 16);
    } else {
#pragma unroll
      for (int q = 0; q < 2; q++) gld16(aptr[q] + aoff, As + q * 4096 + tid * 16);
    }
    if constexpr (B32) {
#pragma unroll
      for (int q = 0; q < 4; q++) gld16(bptr[q] + boff, Bs + q * 4096 + tid * 16);
    } else {
#pragma unroll
      for (int q = 0; q < 2; q++) gld16(bptr[q] + boff, Bs + q * 4096 + tid * 16);
    }
    __syncthreads();

    bf16x8 af[4], bfr[4];
#pragma unroll
    for (int mi = 0; mi < 4; mi++) {
      int row = wr * 64 + mi * 16 + ml;
      if constexpr (A32) af[mi] = cvt8((const float*)As + row * 32 + quad * 8);
      else af[mi] = __builtin_bit_cast(bf16x8, *(const us8*)((const unsigned short*)As + row * 32 + quad * 8));
    }
#pragma unroll
    for (int ni = 0; ni < 4; ni++) {
      int row = wc * 64 + ni * 16 + ml;
      if constexpr (B32) bfr[ni] = cvt8((const float*)Bs + row * 32 + quad * 8);
      else bfr[ni] = __builtin_bit_cast(bf16x8, *(const us8*)((const unsigned short*)Bs + row * 32 + quad * 8));
    }
#pragma unroll
    for (int mi = 0; mi < 4; mi++)
#pragma unroll
      for (int ni = 0; ni < 4; ni++)
        acc[mi][ni] = __builtin_amdgcn_mfma_f32_16x16x32_bf16(af[mi], bfr[ni], acc[mi][ni], 0, 0, 0);
    __syncthreads();
  }

  // epilogue: C/D layout (verified m89): col = lane&15, row = quad*4 + reg
#pragma unroll
  for (int mi = 0; mi < 4; mi++) {
    int ms[4], codes[4];
#pragma unroll
    for (int r = 0; r < 4; r++) {
      ms[r] = rt * 128 + wr * 64 + mi * 16 + quad * 4 + r;
      codes[r] = etok[e * CAP + (ms[r] < cnt ? ms[r] : 0)];
    }
#pragma unroll
    for (int ni = 0; ni < 4; ni++) {
      int n = ct * 128 + wc * 64 + ni * 16 + ml;
      float bv = bias[e * N + n];
#pragma unroll
      for (int r = 0; r < 4; r++) {
        if (ms[r] < cnt) {
          float v = acc[mi][ni][r] + bv;
          if (STAGE == 1) {
            v = 0.5f * v * (1.0f + erff(v * 0.70710678118654752f));  // exact gelu
            hmid[(size_t)codes[r] * IDIM + n] = f2bf(v);
          } else if (YATOM) {
            atomicAdd(&out[(size_t)(codes[r] >> 1) * HDIM + n], tgate[codes[r]] * v);
          } else {
            ybf[(size_t)codes[r] * HDIM + n] = f2bf(v);
          }
        }
      }
    }
  }
}

// ---------------- combine: out[t] = g0*y[2t] + g1*y[2t+1], y is bf16 ----------------
__global__ void combine_k(const unsigned short* __restrict__ y, const float* __restrict__ tgate,
                          float* __restrict__ out) {
  int idx = blockIdx.x * 256 + threadIdx.x;  // T*H/8 threads
  int t = idx >> 7;                          // H/8 = 128 chunks per token
  int c = idx & 127;
  float g0 = tgate[t * 2], g1 = tgate[t * 2 + 1];
  us8 a = *(const us8*)(y + ((size_t)(t * 2) * HDIM) + c * 8);
  us8 b = *(const us8*)(y + ((size_t)(t * 2 + 1) * HDIM) + c * 8);
  float o[8];
#pragma unroll
  for (int i = 0; i < 8; i++) o[i] = g0 * bf2f(a[i]) + g1 * bf2f(b[i]);
  float4* op = (float4*)(out + (size_t)t * HDIM + c * 8);
  op[0] = float4{o[0], o[1], o[2], o[3]};
  op[1] = float4{o[4], o[5], o[6], o[7]};
}

// ---------------- launch ----------------
extern "C" void kernel_launch(void* const* d_in, const int* in_sizes, int n_in,
                              void* d_out, int out_size, void* d_ws, size_t ws_size,
                              hipStream_t stream) {
  const float* x     = (const float*)d_in[0];  // [T, H]
  const float* wg    = (const float*)d_in[1];  // [E, H]
  const float* wfc   = (const float*)d_in[2];  // [E, I, H]
  const float* bfc   = (const float*)d_in[3];  // [E, I]
  const float* wproj = (const float*)d_in[4];  // [E, H, I]
  const float* bproj = (const float*)d_in[5];  // [E, H]
  float* out = (float*)d_out;

  // workspace layout (bytes)
  char* ws = (char*)d_ws;
  size_t off = 0;
  int* counts  = (int*)(ws + off);   off += 4096;
  int* echoice = (int*)(ws + off);   off += (size_t)T_TOK * 4;          // 64 KB
  int* etok    = (int*)(ws + off);   off += (size_t)NEXP * CAP * 4;     // 512 KB
  float* tgate = (float*)(ws + off); off += (size_t)T_TOK * 2 * 4;      // 128 KB
  unsigned short* hmid = (unsigned short*)(ws + off);
  off += (size_t)T_TOK * 2 * IDIM * 2;                                  // 134 MB
  size_t lean_need = off;                                               // ~135 MB
  unsigned short* xbf = (unsigned short*)(ws + off);
  size_t off2 = off + (size_t)T_TOK * HDIM * 2;
  unsigned short* wfcbf = (unsigned short*)(ws + off2);
  off2 += (size_t)NEXP * IDIM * HDIM * 2;
  unsigned short* wprojbf = (unsigned short*)(ws + off2);
  off2 += (size_t)NEXP * HDIM * IDIM * 2;
  size_t full_need = off2;                                              // ~236 MB
  unsigned short* ybf = xbf;   // aliases xbf+wfcbf (dead after GEMM1)

  if (ws_size < lean_need) {
    report_k<<<256, 256, 0, stream>>>(out, (float)(ws_size >> 20), T_TOK * HDIM);
    return;
  }

  bool full = (ws_size >= full_need);

  route1_k<<<T_TOK / 4, 256, 0, stream>>>(x, wg, echoice, tgate, full ? xbf : (unsigned short*)nullptr);
  route2_k<<<NEXP, 256, 0, stream>>>(echoice, counts, etok);

  if (full) {
    // fast path: bf16 operands; non-atomic epilogue via ybf + combine
    cvt_bf16_k<<<4096, 256, 0, stream>>>(wfc,   wfcbf,   NEXP * IDIM * HDIM / 4);
    cvt_bf16_k<<<4096, 256, 0, stream>>>(wproj, wprojbf, NEXP * HDIM * IDIM / 4);
    gemm_k<1, HDIM, IDIM, false, false, false><<<NEXP * 128 * (IDIM / 128), 256, 0, stream>>>(
        xbf, wfcbf, bfc, hmid, ybf, out, tgate, counts, etok);
    gemm_k<2, IDIM, HDIM, false, false, false><<<NEXP * 128 * (HDIM / 128), 256, 0, stream>>>(
        hmid, wprojbf, bproj, hmid, ybf, out, tgate, counts, etok);
    combine_k<<<T_TOK * HDIM / 8 / 256, 256, 0, stream>>>(ybf, tgate, out);
  } else {
    // lean path: stage fp32 operands, convert at fragment read; atomic epilogue
    zero_out_k<<<T_TOK * HDIM / 1024, 256, 0, stream>>>((float4*)out);
    gemm_k<1, HDIM, IDIM, true, true, true><<<NEXP * 128 * (IDIM / 128), 256, 0, stream>>>(
        x, wfc, bfc, hmid, ybf, out, tgate, counts, etok);
    gemm_k<2, IDIM, HDIM, false, true, true><<<NEXP * 128 * (HDIM / 128), 256, 0, stream>>>(
        hmid, wproj, bproj, hmid, ybf, out, tgate, counts, etok);
  }
}

// Round 5
// 702.164 us; speedup vs baseline: 1.5573x; 1.0251x over previous
//
#include <hip/hip_runtime.h>
#include <math.h>

// ---------------- problem constants ----------------
#define T_TOK 16384   // B*S tokens
#define HDIM  1024
#define IDIM  2048
#define NEXP  8
#define CAP   16384   // per-expert capacity (each token at most once per expert)

typedef __bf16 bf16x8 __attribute__((ext_vector_type(8)));
typedef float  f32x4  __attribute__((ext_vector_type(4)));
typedef unsigned short us8 __attribute__((ext_vector_type(8)));

__device__ __forceinline__ unsigned short f2bf(float f) {
  unsigned int u = __builtin_bit_cast(unsigned int, f);
  u = (u + 0x7FFFu + ((u >> 16) & 1u)) >> 16;   // RNE
  return (unsigned short)u;
}

__device__ __forceinline__ float bf2f(unsigned short u) {
  return __builtin_bit_cast(float, (unsigned int)u << 16);
}

__device__ __forceinline__ void gld16(const void* g, void* l) {
  __builtin_amdgcn_global_load_lds(
      (const __attribute__((address_space(1))) void*)(g),
      (__attribute__((address_space(3))) void*)(l), 16, 0, 0);
}

// read 8 consecutive fp32 from LDS, convert to bf16x8 (RNE)
__device__ __forceinline__ bf16x8 cvt8(const float* p) {
  f32x4 lo = *(const f32x4*)p;
  f32x4 hi = *(const f32x4*)(p + 4);
  us8 t;
  t[0] = f2bf(lo[0]); t[1] = f2bf(lo[1]); t[2] = f2bf(lo[2]); t[3] = f2bf(lo[3]);
  t[4] = f2bf(hi[0]); t[5] = f2bf(hi[1]); t[6] = f2bf(hi[2]); t[7] = f2bf(hi[3]);
  return __builtin_bit_cast(bf16x8, t);
}

// ---------------- tiny utility kernels ----------------
__global__ void zero_out_k(float4* out) {   // one float4 per thread
  out[blockIdx.x * 256 + threadIdx.x] = float4{0.f, 0.f, 0.f, 0.f};
}

__global__ void report_k(float* out, float v, int n) {  // diagnostic: absmax == ws MB
  int idx = blockIdx.x * blockDim.x + threadIdx.x;
  int stride = gridDim.x * blockDim.x;
  for (int i = idx; i < n; i += stride) out[i] = v;
}

// ---------------- fp32 -> bf16 conversion (grid-stride, float4) ----------------
__global__ void cvt_bf16_k(const float* __restrict__ src, unsigned short* __restrict__ dst, int n4) {
  int idx = blockIdx.x * blockDim.x + threadIdx.x;
  int stride = gridDim.x * blockDim.x;
  for (int i = idx; i < n4; i += stride) {
    float4 v = ((const float4*)src)[i];
    ushort4 o;
    o.x = f2bf(v.x); o.y = f2bf(v.y); o.z = f2bf(v.z); o.w = f2bf(v.w);
    ((ushort4*)dst)[i] = o;
  }
}

// ---------------- routing pass 1: fp32 logits, top-2, softmax; also emits xbf ----------------
__global__ void route1_k(const float* __restrict__ x, const float* __restrict__ wg,
                         int* __restrict__ echoice, float* __restrict__ tgate,
                         unsigned short* __restrict__ xbf) {
  __shared__ __align__(16) float wgl[NEXP * HDIM];   // 32 KB
  int tid = threadIdx.x;
  for (int i = tid; i < NEXP * HDIM / 4; i += 256)
    ((float4*)wgl)[i] = ((const float4*)wg)[i];
  __syncthreads();

  int wave = tid >> 6, lane = tid & 63;
  int t = blockIdx.x * 4 + wave;

  float accv[NEXP];
#pragma unroll
  for (int e = 0; e < NEXP; e++) accv[e] = 0.f;
  const float* xr = x + (size_t)t * HDIM;
#pragma unroll 4
  for (int j = 0; j < HDIM / 64; j++) {
    float xv = xr[lane + j * 64];
    if (xbf) xbf[(size_t)t * HDIM + lane + j * 64] = f2bf(xv);
#pragma unroll
    for (int e = 0; e < NEXP; e++) accv[e] += xv * wgl[e * HDIM + lane + j * 64];
  }
#pragma unroll
  for (int off = 1; off < 64; off <<= 1) {
#pragma unroll
    for (int e = 0; e < NEXP; e++) accv[e] += __shfl_xor(accv[e], off, 64);
  }

  if (lane == 0) {
    int e0 = 0; float v0 = accv[0];
#pragma unroll
    for (int e = 1; e < NEXP; e++) if (accv[e] > v0) { v0 = accv[e]; e0 = e; }
    int e1 = -1; float v1 = -3.4e38f;
#pragma unroll
    for (int e = 0; e < NEXP; e++) if (e != e0 && accv[e] > v1) { v1 = accv[e]; e1 = e; }
    float ex = expf(v1 - v0);
    echoice[t] = e0 | (e1 << 8);
    tgate[t * 2]     = 1.f / (1.f + ex);
    tgate[t * 2 + 1] = ex / (1.f + ex);
  }
}

// ---------------- routing pass 2: deterministic per-expert compaction ----------------
__global__ void route2_k(const int* __restrict__ echoice, int* __restrict__ counts,
                         int* __restrict__ etok) {
  int E = blockIdx.x;
  int tid = threadIdx.x, lane = tid & 63, wv = tid >> 6;
  __shared__ int base;
  __shared__ int wsum[4];
  if (tid == 0) base = 0;
  __syncthreads();
  for (int t0 = 0; t0 < T_TOK; t0 += 256) {
    int t = t0 + tid;
    int ec = echoice[t];
    int e0 = ec & 255, e1 = (ec >> 8) & 255;
    bool m = (e0 == E) | (e1 == E);
    int code = t * 2 + (e1 == E ? 1 : 0);
    unsigned long long mask = __ballot(m);
    if (lane == 0) wsum[wv] = __popcll(mask);
    int lpre = __popcll(mask & ((1ull << lane) - 1ull));
    __syncthreads();
    int wbase = 0;
#pragma unroll
    for (int w = 0; w < 4; w++) if (w < wv) wbase += wsum[w];
    int total = wsum[0] + wsum[1] + wsum[2] + wsum[3];
    if (m) etok[E * CAP + base + wbase + lpre] = code;
    __syncthreads();
    if (tid == 0) base += total;
    __syncthreads();
  }
  if (tid == 0) counts[E] = base;
}

// ---------------- grouped GEMM (128x128 tile, m97 recipe + T1 swizzle + BK=64 super-step) ----------------
// ROUND-5 CHANGE vs round 4 (719.8us): on the bf16-bf16 fast path only, stage
// TWO k-subtiles (2 x 8KB A + 2 x 8KB B, LDS 16->32KB) behind ONE barrier pair
// and compute both 16-MFMA clusters before the next drain.  m233 showed the
// 2-phase critical path is ~72% stage+vmcnt+barrier overhead; halving the
// drain count amortizes each ~300cy drain over ~620cy of MFMA instead of
// ~310cy.  Layout, staging pattern, fragment reads, epilogue: identical to
// round 4 (the proven config).  ks-compute loop kept ROLLED (#pragma unroll 1)
// so af/bfr fragment registers are reused -> VGPR count unchanged (occupancy
// is register-limited at ~2.5 blocks/CU; LDS 32KB still allows 5).
template <int STAGE, int K, int N, bool A32, bool B32, bool YATOM>
__global__ __launch_bounds__(256)
void gemm_k(const void* __restrict__ Ap_, const void* __restrict__ Wp_,
            const float* __restrict__ bias, unsigned short* __restrict__ hmid,
            unsigned short* __restrict__ ybf, float* __restrict__ out,
            const float* __restrict__ tgate,
            const int* __restrict__ counts, const int* __restrict__ etok) {
  constexpr int NT = N / 128;
  constexpr int KSUB = (A32 || B32) ? 1 : 2;       // k-subtiles per barrier pair
  constexpr int ASZ = A32 ? 16384 : 8192 * KSUB;   // 16KB either way
  constexpr int BSZ = B32 ? 16384 : 8192 * KSUB;
  __shared__ __align__(16) char smem[ASZ + BSZ];
  char* As = smem;
  char* Bs = smem + ASZ;

  // T1: XCD-aware bijective swizzle (8 XCDs, grid % 8 == 0 by construction)
  int nwg = gridDim.x;
  int bid = blockIdx.x;
  int swz = (bid & 7) * (nwg >> 3) + (bid >> 3);

  int e  = swz / (128 * NT);
  int bi = swz % (128 * NT);
  int rt = bi / NT, ct = bi % NT;
  int cnt = counts[e];
  if (rt * 128 >= cnt) return;

  int tid = threadIdx.x;
  int lane = tid & 63, wv = tid >> 6;
  int wr = wv >> 1, wc = wv & 1;          // 2x2 wave grid, 64x64 per wave
  int quad = lane >> 4, ml = lane & 15;

  // ---- staging pointers (LDS byte offset is q*4096 + tid*16 for both widths) ----
  const char* aptr[4];
  if constexpr (A32) {
    int srow = tid >> 3, seg = tid & 7;   // 32 rows per quarter, 8x16B per row
    const float* Af = (const float*)Ap_;
#pragma unroll
    for (int q = 0; q < 4; q++) {
      int r = rt * 128 + q * 32 + srow;
      int code = etok[e * CAP + (r < cnt ? r : cnt - 1)];
      int row = (STAGE == 1) ? (code >> 1) : code;
      aptr[q] = (const char*)(Af + (size_t)row * K + seg * 4);
    }
  } else {
    int srow = tid >> 2, seg = tid & 3;   // 64 rows per half, 4x16B per row
    const unsigned short* Ab = (const unsigned short*)Ap_;
#pragma unroll
    for (int q = 0; q < 2; q++) {
      int r = rt * 128 + q * 64 + srow;
      int code = etok[e * CAP + (r < cnt ? r : cnt - 1)];
      int row = (STAGE == 1) ? (code >> 1) : code;
      aptr[q] = (const char*)(Ab + (size_t)row * K + seg * 8);
    }
  }
  const char* bptr[4];
  if constexpr (B32) {
    int srow = tid >> 3, seg = tid & 7;
    const float* Wf = (const float*)Wp_;
#pragma unroll
    for (int q = 0; q < 4; q++)
      bptr[q] = (const char*)(Wf + ((size_t)e * N + ct * 128 + q * 32 + srow) * K + seg * 4);
  } else {
    int srow = tid >> 2, seg = tid & 3;
    const unsigned short* Wb = (const unsigned short*)Wp_;
#pragma unroll
    for (int q = 0; q < 2; q++)
      bptr[q] = (const char*)(Wb + ((size_t)e * N + ct * 128 + q * 64 + srow) * K + seg * 8);
  }

  f32x4 acc[4][4] = {};

  for (int k0 = 0; k0 < K; k0 += 32 * KSUB) {
    // ---- stage KSUB k-subtiles, one drain for all ----
#pragma unroll
    for (int ks = 0; ks < KSUB; ks++) {
      size_t aoff = (size_t)(k0 + ks * 32) * (A32 ? 4 : 2);
      if constexpr (A32) {
#pragma unroll
        for (int q = 0; q < 4; q++) gld16(aptr[q] + aoff, As + q * 4096 + tid * 16);
      } else {
#pragma unroll
        for (int q = 0; q < 2; q++) gld16(aptr[q] + aoff, As + ks * 8192 + q * 4096 + tid * 16);
      }
    }
#pragma unroll
    for (int ks = 0; ks < KSUB; ks++) {
      size_t boff = (size_t)(k0 + ks * 32) * (B32 ? 4 : 2);
      if constexpr (B32) {
#pragma unroll
        for (int q = 0; q < 4; q++) gld16(bptr[q] + boff, Bs + q * 4096 + tid * 16);
      } else {
#pragma unroll
        for (int q = 0; q < 2; q++) gld16(bptr[q] + boff, Bs + ks * 8192 + q * 4096 + tid * 16);
      }
    }
    __syncthreads();

    // ---- compute KSUB sub-steps (rolled: fragment regs reused across ks) ----
#pragma unroll 1
    for (int ks = 0; ks < KSUB; ks++) {
      const char* Ab = As + ks * 8192;
      const char* Bb = Bs + ks * 8192;
      bf16x8 af[4], bfr[4];
#pragma unroll
      for (int mi = 0; mi < 4; mi++) {
        int row = wr * 64 + mi * 16 + ml;
        if constexpr (A32) af[mi] = cvt8((const float*)As + row * 32 + quad * 8);
        else af[mi] = __builtin_bit_cast(bf16x8, *(const us8*)((const unsigned short*)Ab + row * 32 + quad * 8));
      }
#pragma unroll
      for (int ni = 0; ni < 4; ni++) {
        int row = wc * 64 + ni * 16 + ml;
        if constexpr (B32) bfr[ni] = cvt8((const float*)Bs + row * 32 + quad * 8);
        else bfr[ni] = __builtin_bit_cast(bf16x8, *(const us8*)((const unsigned short*)Bb + row * 32 + quad * 8));
      }
#pragma unroll
      for (int mi = 0; mi < 4; mi++)
#pragma unroll
        for (int ni = 0; ni < 4; ni++)
          acc[mi][ni] = __builtin_amdgcn_mfma_f32_16x16x32_bf16(af[mi], bfr[ni], acc[mi][ni], 0, 0, 0);
    }
    __syncthreads();
  }

  // epilogue: C/D layout (verified m89): col = lane&15, row = quad*4 + reg
#pragma unroll
  for (int mi = 0; mi < 4; mi++) {
    int ms[4], codes[4];
#pragma unroll
    for (int r = 0; r < 4; r++) {
      ms[r] = rt * 128 + wr * 64 + mi * 16 + quad * 4 + r;
      codes[r] = etok[e * CAP + (ms[r] < cnt ? ms[r] : 0)];
    }
#pragma unroll
    for (int ni = 0; ni < 4; ni++) {
      int n = ct * 128 + wc * 64 + ni * 16 + ml;
      float bv = bias[e * N + n];
#pragma unroll
      for (int r = 0; r < 4; r++) {
        if (ms[r] < cnt) {
          float v = acc[mi][ni][r] + bv;
          if (STAGE == 1) {
            v = 0.5f * v * (1.0f + erff(v * 0.70710678118654752f));  // exact gelu
            hmid[(size_t)codes[r] * IDIM + n] = f2bf(v);
          } else if (YATOM) {
            atomicAdd(&out[(size_t)(codes[r] >> 1) * HDIM + n], tgate[codes[r]] * v);
          } else {
            ybf[(size_t)codes[r] * HDIM + n] = f2bf(v);
          }
        }
      }
    }
  }
}

// ---------------- combine: out[t] = g0*y[2t] + g1*y[2t+1], y is bf16 ----------------
__global__ void combine_k(const unsigned short* __restrict__ y, const float* __restrict__ tgate,
                          float* __restrict__ out) {
  int idx = blockIdx.x * 256 + threadIdx.x;  // T*H/8 threads
  int t = idx >> 7;                          // H/8 = 128 chunks per token
  int c = idx & 127;
  float g0 = tgate[t * 2], g1 = tgate[t * 2 + 1];
  us8 a = *(const us8*)(y + ((size_t)(t * 2) * HDIM) + c * 8);
  us8 b = *(const us8*)(y + ((size_t)(t * 2 + 1) * HDIM) + c * 8);
  float o[8];
#pragma unroll
  for (int i = 0; i < 8; i++) o[i] = g0 * bf2f(a[i]) + g1 * bf2f(b[i]);
  float4* op = (float4*)(out + (size_t)t * HDIM + c * 8);
  op[0] = float4{o[0], o[1], o[2], o[3]};
  op[1] = float4{o[4], o[5], o[6], o[7]};
}

// ---------------- launch ----------------
extern "C" void kernel_launch(void* const* d_in, const int* in_sizes, int n_in,
                              void* d_out, int out_size, void* d_ws, size_t ws_size,
                              hipStream_t stream) {
  const float* x     = (const float*)d_in[0];  // [T, H]
  const float* wg    = (const float*)d_in[1];  // [E, H]
  const float* wfc   = (const float*)d_in[2];  // [E, I, H]
  const float* bfc   = (const float*)d_in[3];  // [E, I]
  const float* wproj = (const float*)d_in[4];  // [E, H, I]
  const float* bproj = (const float*)d_in[5];  // [E, H]
  float* out = (float*)d_out;

  // workspace layout (bytes)
  char* ws = (char*)d_ws;
  size_t off = 0;
  int* counts  = (int*)(ws + off);   off += 4096;
  int* echoice = (int*)(ws + off);   off += (size_t)T_TOK * 4;          // 64 KB
  int* etok    = (int*)(ws + off);   off += (size_t)NEXP * CAP * 4;     // 512 KB
  float* tgate = (float*)(ws + off); off += (size_t)T_TOK * 2 * 4;      // 128 KB
  unsigned short* hmid = (unsigned short*)(ws + off);
  off += (size_t)T_TOK * 2 * IDIM * 2;                                  // 134 MB
  size_t lean_need = off;                                               // ~135 MB
  unsigned short* xbf = (unsigned short*)(ws + off);
  size_t off2 = off + (size_t)T_TOK * HDIM * 2;
  unsigned short* wfcbf = (unsigned short*)(ws + off2);
  off2 += (size_t)NEXP * IDIM * HDIM * 2;
  unsigned short* wprojbf = (unsigned short*)(ws + off2);
  off2 += (size_t)NEXP * HDIM * IDIM * 2;
  size_t full_need = off2;                                              // ~236 MB
  unsigned short* ybf = xbf;   // aliases xbf+wfcbf (dead after GEMM1)

  if (ws_size < lean_need) {
    report_k<<<256, 256, 0, stream>>>(out, (float)(ws_size >> 20), T_TOK * HDIM);
    return;
  }

  bool full = (ws_size >= full_need);

  route1_k<<<T_TOK / 4, 256, 0, stream>>>(x, wg, echoice, tgate, full ? xbf : (unsigned short*)nullptr);
  route2_k<<<NEXP, 256, 0, stream>>>(echoice, counts, etok);

  if (full) {
    // fast path: bf16 operands; non-atomic epilogue via ybf + combine
    cvt_bf16_k<<<4096, 256, 0, stream>>>(wfc,   wfcbf,   NEXP * IDIM * HDIM / 4);
    cvt_bf16_k<<<4096, 256, 0, stream>>>(wproj, wprojbf, NEXP * HDIM * IDIM / 4);
    gemm_k<1, HDIM, IDIM, false, false, false><<<NEXP * 128 * (IDIM / 128), 256, 0, stream>>>(
        xbf, wfcbf, bfc, hmid, ybf, out, tgate, counts, etok);
    gemm_k<2, IDIM, HDIM, false, false, false><<<NEXP * 128 * (HDIM / 128), 256, 0, stream>>>(
        hmid, wprojbf, bproj, hmid, ybf, out, tgate, counts, etok);
    combine_k<<<T_TOK * HDIM / 8 / 256, 256, 0, stream>>>(ybf, tgate, out);
  } else {
    // lean path: stage fp32 operands, convert at fragment read; atomic epilogue
    zero_out_k<<<T_TOK * HDIM / 1024, 256, 0, stream>>>((float4*)out);
    gemm_k<1, HDIM, IDIM, true, true, true><<<NEXP * 128 * (IDIM / 128), 256, 0, stream>>>(
        x, wfc, bfc, hmid, ybf, out, tgate, counts, etok);
    gemm_k<2, IDIM, HDIM, false, true, true><<<NEXP * 128 * (HDIM / 128), 256, 0, stream>>>(
        hmid, wproj, bproj, hmid, ybf, out, tgate, counts, etok);
  }
}